// Round 6
// baseline (106.677 us; speedup 1.0000x reference)
//
#include <hip/hip_runtime.h>
#include <math.h>

#define BATCH 512    // post-reshape scan lanes
#define FRAGS 512    // fragments per chain
#define GROUP 32     // fragments per scan group == frags per block
#define NGRP  (FRAGS/GROUP)   // 16 groups
#define BTILE 16     // batch lanes per block
#define NTILE (BATCH/BTILE)   // 32 b-tiles
#define RPF   4      // residues per fragment (L=2048)
#define NPTS  (3*RPF)         // 12 points per fragment
#define READY 0x5EADBEEF

// Rigid transform: 12 floats, R row-major r[i*3+j], t=[9..11]. x' = Rx + t.
// compose(A,B): A is the EARLIER prefix, B the later. (Verified R5-R9.)
__device__ __forceinline__ void compose(const float* A, const float* B, float* D) {
    float d[12];
    #pragma unroll
    for (int i = 0; i < 3; ++i) {
        #pragma unroll
        for (int j = 0; j < 3; ++j)
            d[i*3+j] = A[i*3+0]*B[0*3+j] + A[i*3+1]*B[1*3+j] + A[i*3+2]*B[2*3+j];
        d[9+i] = A[i*3+0]*B[9] + A[i*3+1]*B[10] + A[i*3+2]*B[11] + A[9+i];
    }
    #pragma unroll
    for (int k = 0; k < 12; ++k) D[k] = d[k];
}

__device__ __forceinline__ void set_identity(float* D) {
    D[0]=1.f; D[1]=0.f; D[2]=0.f;
    D[3]=0.f; D[4]=1.f; D[5]=0.f;
    D[6]=0.f; D[7]=0.f; D[8]=1.f;
    D[9]=0.f; D[10]=0.f; D[11]=0.f;
}

__device__ __forceinline__ void frame_of(
    float ax, float ay, float az,
    float bx, float by, float bz,
    float cx, float cy, float cz,
    float* out /*12*/)
{
    float bcx = cx - bx, bcy = cy - by, bcz = cz - bz;
    float inv = rsqrtf(bcx*bcx + bcy*bcy + bcz*bcz + 1e-12f);
    bcx *= inv; bcy *= inv; bcz *= inv;
    float bax = bx - ax, bay = by - ay, baz = bz - az;
    float nx = bay*bcz - baz*bcy;
    float ny = baz*bcx - bax*bcz;
    float nz = bax*bcy - bay*bcx;
    inv = rsqrtf(nx*nx + ny*ny + nz*nz + 1e-12f);
    nx *= inv; ny *= inv; nz *= inv;
    float mx = ny*bcz - nz*bcy;
    float my = nz*bcx - nx*bcz;
    float mz = nx*bcy - ny*bcx;
    out[0] = bcx; out[1] = mx; out[2] = nx;
    out[3] = bcy; out[4] = my; out[5] = ny;
    out[6] = bcz; out[7] = mz; out[8] = nz;
    out[9] = cx; out[10] = cy; out[11] = cz;
}

__device__ __forceinline__ void nerf_step(
    float ax, float ay, float az,
    float bx, float by, float bz,
    float cx, float cy, float cz,
    float px, float py, float pz,
    float& ox, float& oy, float& oz)
{
    float bcx = cx - bx, bcy = cy - by, bcz = cz - bz;
    float inv = rsqrtf(bcx*bcx + bcy*bcy + bcz*bcz + 1e-12f);
    bcx *= inv; bcy *= inv; bcz *= inv;
    float bax = bx - ax, bay = by - ay, baz = bz - az;
    float nx = bay*bcz - baz*bcy;
    float ny = baz*bcx - bax*bcz;
    float nz = bax*bcy - bay*bcx;
    inv = rsqrtf(nx*nx + ny*ny + nz*nz + 1e-12f);
    nx *= inv; ny *= inv; nz *= inv;
    float mx = ny*bcz - nz*bcy;
    float my = nz*bcx - nx*bcz;
    float mz = nx*bcy - ny*bcx;
    ox = bcx*px + mx*py + nx*pz + cx;
    oy = bcy*px + my*py + ny*pz + cy;
    oz = bcz*px + mz*py + nz*pz + cz;
}

// Per-lane permuted bond constants. Reshape (L,B,3,3)->(3L,B,3) makes scan
// lane b at residue l, step k consume dih flat[l*1536 + 512k + b]; bond-const
// index = (512k+b)%3 -> pattern d = {b%3, (b+2)%3, (b+1)%3}. (Verified R5.)
__device__ __forceinline__ void lane_consts(int b, float* rcl, float* rsl) {
    const float PI = 3.14159265358979323846f;
    float rc[3], rs[3];
    rc[0] = 145.801f * cosf(PI - 2.124f); rs[0] = 145.801f * sinf(PI - 2.124f);
    rc[1] = 152.326f * cosf(PI - 1.941f); rs[1] = 152.326f * sinf(PI - 1.941f);
    rc[2] = 132.868f * cosf(PI - 2.028f); rs[2] = 132.868f * sinf(PI - 2.028f);
    const int d0 = b % 3, d1 = (b + 2) % 3, d2 = (b + 1) % 3;
    rcl[0] = rc[d0]; rcl[1] = rc[d1]; rcl[2] = rc[d2];
    rsl[0] = rs[d0]; rsl[1] = rs[d1]; rsl[2] = rs[d2];
}

// Single-dispatch grid scan via flag lookback (no cooperative launch — R8
// showed hipLaunchCooperativeKernel no-ops under graph capture).
//
// R15 geometry: RPF=4, FRAGS=512, GROUP=32, BTILE=16 -> 512 blocks x 512
// threads = 2 blocks/CU = 4 waves/SIMD (was 2), serial chain halved to 12
// steps. Deadlock-safe: per-CU capacity is 3 blocks (LDS 53KB -> floor(160/53)
// =3; threads 2048/512=4), so all 512 blocks are co-resident with slack; and
// the wait-DAG points only to lower blockIdx (lower g), which the CP
// dispatches first. Flags poisoned 0xAA pre-launch (!= READY) self-reset.
//
// Kept from R14 (measured win, 43.9->~36us): RELAXED spin + one acquire
// fence (acquire-spin cache-inv storm was ~8us). Kept: points-in-regs,
// NT dihedral loads, inclusive scan1 + pprev, parallel scan2, wave-level
// release. Changed: scalar NT stores -> plain 12B vector stores (3x fewer
// store instrs; NT partial-line suspicion from R0->R1).
__global__ void __launch_bounds__(GROUP * BTILE) coord_onepass(
    const float* __restrict__ dih, float* __restrict__ T,
    int* __restrict__ flags, float* __restrict__ out)
{
    const int btile = blockIdx.x & (NTILE - 1);
    const int g     = blockIdx.x >> 5;                 // NTILE==32
    const int bsub  = threadIdx.x & (BTILE - 1);
    const int j     = threadIdx.x >> 4;                // BTILE==16
    const int f     = g * GROUP + j;
    const int b     = btile * BTILE + bsub;

    __shared__ float BufA[GROUP * BTILE * 13];         // stride 13: conflict-free
    __shared__ float BufB[GROUP * BTILE * 13];
    float* rowA = &BufA[(size_t)threadIdx.x * 13];
    float* rowB = &BufB[(size_t)threadIdx.x * 13];

    float rcl[3], rsl[3];
    lane_consts(b, rcl, rsl);

    // ---- Prefetch this fragment's dihedrals (12 regs, dead after stage 1) ----
    float dd[NPTS];
    #pragma unroll
    for (int r = 0; r < RPF; ++r) {
        const float* src = dih + (size_t)(f * RPF + r) * (3 * BATCH) + b;
        dd[r*3 + 0] = __builtin_nontemporal_load(src);
        dd[r*3 + 1] = __builtin_nontemporal_load(src + BATCH);
        dd[r*3 + 2] = __builtin_nontemporal_load(src + 2 * BATCH);
    }

    // ---- Stage 1: local chain, 12 points kept in registers (36 regs) ----
    float lx[NPTS], ly[NPTS], lz[NPTS];

    float ax = -0.70710678118654752f, ay = 1.22474487139158905f, az = 0.0f;
    float bx = -1.41421356237309505f, by = 0.0f, bz = 0.0f;
    float cx = 0.0f, cy = 0.0f, cz = 0.0f;

    #pragma unroll
    for (int r = 0; r < RPF; ++r) {
        #pragma unroll
        for (int k = 0; k < 3; ++k) {
            float sn, cs;
            __sincosf(dd[r*3 + k], &sn, &cs);
            float ox, oy, oz;
            nerf_step(ax, ay, az, bx, by, bz, cx, cy, cz,
                      rcl[k], cs * rsl[k], sn * rsl[k], ox, oy, oz);
            ax = bx; ay = by; az = bz;
            bx = cx; by = cy; bz = cz;
            cx = ox; cy = oy; cz = oz;
            lx[r*3 + k] = ox; ly[r*3 + k] = oy; lz[r*3 + k] = oz;
        }
    }

    float cur[12];                       // running inclusive prefix (regs)
    frame_of(ax, ay, az, bx, by, bz, cx, cy, cz, cur);

    // ---- Scan 1: inclusive Hillis-Steele over j (32 rows, 5 rounds),
    //      register-tracked, ping-pong A/B. WAR-safe: readers of a buffer
    //      are separated from its next write by >=1 barrier. ----
    #pragma unroll
    for (int k = 0; k < 12; ++k) rowA[k] = cur[k];
    __syncthreads();
    if (j >= 1) compose(&BufA[(size_t)(threadIdx.x - 1*BTILE) * 13], cur, cur);

    #pragma unroll
    for (int k = 0; k < 12; ++k) rowB[k] = cur[k];
    __syncthreads();
    if (j >= 2) compose(&BufB[(size_t)(threadIdx.x - 2*BTILE) * 13], cur, cur);

    #pragma unroll
    for (int k = 0; k < 12; ++k) rowA[k] = cur[k];
    __syncthreads();
    if (j >= 4) compose(&BufA[(size_t)(threadIdx.x - 4*BTILE) * 13], cur, cur);

    #pragma unroll
    for (int k = 0; k < 12; ++k) rowB[k] = cur[k];
    __syncthreads();
    if (j >= 8) compose(&BufB[(size_t)(threadIdx.x - 8*BTILE) * 13], cur, cur);

    #pragma unroll
    for (int k = 0; k < 12; ++k) rowA[k] = cur[k];
    __syncthreads();
    if (j >= 16) compose(&BufA[(size_t)(threadIdx.x - 16*BTILE) * 13], cur, cur);

    // final publish of inclusive prefixes -> B
    #pragma unroll
    for (int k = 0; k < 12; ++k) rowB[k] = cur[k];
    __syncthreads();

    // P[f-1] for this thread (row j-1), grabbed before B is reused by scan2
    float pprev[12];
    if (j > 0) {
        #pragma unroll
        for (int k = 0; k < 12; ++k)
            pprev[k] = BufB[(size_t)(threadIdx.x - BTILE) * 13 + k];
    }

    // ---- Publish group total T_g (row 31 = lanes 48..63 of wave 7) +
    //      wave-level release: the release store's wave-wide vmcnt(0)
    //      orders sibling lanes' T stores before the flag is visible.
    //      Last group's total is dead. ----
    if (j == GROUP - 1 && g < NGRP - 1) {
        #pragma unroll
        for (int k = 0; k < 12; ++k)
            __hip_atomic_store(&T[((size_t)g * 12 + k) * BATCH + b], cur[k],
                               __ATOMIC_RELAXED, __HIP_MEMORY_SCOPE_AGENT);
        if (bsub == 0)
            __hip_atomic_store(&flags[g * NTILE + btile], READY,
                               __ATOMIC_RELEASE, __HIP_MEMORY_SCOPE_AGENT);
    }

    // ---- Scan 2 (g>0; uniform branch): parallel exclusive prefix of the
    //      16 group totals. Row j holds T_j (j<g) else identity; rows >=16
    //      participate harmlessly (identity, results unused). RELAXED spin;
    //      ONE acquire fence after the flag is seen (R14 win). ----
    float G[12];
    if (g == 0) {
        if (j == 0) set_identity(G);
        else {
            #pragma unroll
            for (int k = 0; k < 12; ++k) G[k] = pprev[k];
        }
    } else {
        float cur2[12];
        if (j < g) {
            while (__hip_atomic_load(&flags[j * NTILE + btile],
                                     __ATOMIC_RELAXED, __HIP_MEMORY_SCOPE_AGENT)
                   != READY) {
                __builtin_amdgcn_s_sleep(1);
            }
            __builtin_amdgcn_fence(__ATOMIC_ACQUIRE, "agent");
            #pragma unroll
            for (int k = 0; k < 12; ++k)
                cur2[k] = __hip_atomic_load(&T[((size_t)j * 12 + k) * BATCH + b],
                                            __ATOMIC_RELAXED, __HIP_MEMORY_SCOPE_AGENT);
        } else {
            set_identity(cur2);
        }

        // ping-pong rounds: A, B, A, B (B's final-prefix data was consumed
        // into pprev before any thread can pass the first barrier below)
        #pragma unroll
        for (int k = 0; k < 12; ++k) rowA[k] = cur2[k];
        __syncthreads();
        if (j >= 1) compose(&BufA[(size_t)(threadIdx.x - 1*BTILE) * 13], cur2, cur2);

        #pragma unroll
        for (int k = 0; k < 12; ++k) rowB[k] = cur2[k];
        __syncthreads();
        if (j >= 2) compose(&BufB[(size_t)(threadIdx.x - 2*BTILE) * 13], cur2, cur2);

        #pragma unroll
        for (int k = 0; k < 12; ++k) rowA[k] = cur2[k];
        __syncthreads();
        if (j >= 4) compose(&BufA[(size_t)(threadIdx.x - 4*BTILE) * 13], cur2, cur2);

        #pragma unroll
        for (int k = 0; k < 12; ++k) rowB[k] = cur2[k];
        __syncthreads();
        if (j >= 8) compose(&BufB[(size_t)(threadIdx.x - 8*BTILE) * 13], cur2, cur2);

        // broadcast row g-1 (same-address LDS reads across j: free broadcast)
        #pragma unroll
        for (int k = 0; k < 12; ++k) rowA[k] = cur2[k];
        __syncthreads();
        float E[12];
        #pragma unroll
        for (int k = 0; k < 12; ++k)
            E[k] = BufA[(size_t)((g - 1) * BTILE + bsub) * 13 + k];

        if (j == 0) {
            #pragma unroll
            for (int k = 0; k < 12; ++k) G[k] = E[k];
        } else {
            compose(E, pprev, G);
        }
    }

    // ---- Transform register-held points, 12B vector stores (16 lanes
    //      write a contiguous 192B span per row) ----
    struct F3 { float x, y, z; };
    #pragma unroll
    for (int q = 0; q < NPTS; ++q) {
        float ox = lx[q], oy = ly[q], oz = lz[q];
        float gx = G[0]*ox + G[1]*oy + G[2]*oz + G[9];
        float gy = G[3]*ox + G[4]*oy + G[5]*oz + G[10];
        float gz = G[6]*ox + G[7]*oy + G[8]*oz + G[11];
        size_t n = (size_t)f * NPTS + q;               // scan step index
        float* dst = out + (n * BATCH + b) * 3;
        *reinterpret_cast<F3*>(dst) = F3{gx, gy, gz};
    }
}

extern "C" void kernel_launch(void* const* d_in, const int* in_sizes, int n_in,
                              void* d_out, int out_size, void* d_ws, size_t ws_size,
                              hipStream_t stream) {
    const float* dih = (const float*)d_in[0];
    float* out = (float*)d_out;
    float* T = (float*)d_ws;                           // NGRP*12*BATCH floats
    int* flags = (int*)(T + (size_t)NGRP * 12 * BATCH); // NGRP*NTILE ints

    coord_onepass<<<dim3(NGRP * NTILE), dim3(GROUP * BTILE), 0, stream>>>(
        dih, T, flags, out);
    (void)ws_size; (void)n_in; (void)out_size; (void)in_sizes;
}

// Round 7
// 96.928 us; speedup vs baseline: 1.1006x; 1.1006x over previous
//
#include <hip/hip_runtime.h>
#include <math.h>

#define BATCH 512    // post-reshape scan lanes
#define FRAGS 256    // fragments per chain
#define GROUP 16     // fragments per scan group == frags per block
#define NGRP  (FRAGS/GROUP)   // 16 groups
#define BTILE 32     // batch lanes per block
#define NTILE (BATCH/BTILE)   // 16 b-tiles
#define RPF   8      // residues per fragment (L=2048)
#define NPTS  (3*RPF)         // 24 points per fragment
#define HALF  (NPTS/2)        // 12 points per half-chain
#define READY 0x5EADBEEF

// Rigid transform: 12 floats, R row-major r[i*3+j], t=[9..11]. x' = Rx + t.
// compose(A,B): A is the EARLIER prefix, B the later. (Verified R5-R9.)
__device__ __forceinline__ void compose(const float* A, const float* B, float* D) {
    float d[12];
    #pragma unroll
    for (int i = 0; i < 3; ++i) {
        #pragma unroll
        for (int j = 0; j < 3; ++j)
            d[i*3+j] = A[i*3+0]*B[0*3+j] + A[i*3+1]*B[1*3+j] + A[i*3+2]*B[2*3+j];
        d[9+i] = A[i*3+0]*B[9] + A[i*3+1]*B[10] + A[i*3+2]*B[11] + A[9+i];
    }
    #pragma unroll
    for (int k = 0; k < 12; ++k) D[k] = d[k];
}

__device__ __forceinline__ void set_identity(float* D) {
    D[0]=1.f; D[1]=0.f; D[2]=0.f;
    D[3]=0.f; D[4]=1.f; D[5]=0.f;
    D[6]=0.f; D[7]=0.f; D[8]=1.f;
    D[9]=0.f; D[10]=0.f; D[11]=0.f;
}

__device__ __forceinline__ void frame_of(
    float ax, float ay, float az,
    float bx, float by, float bz,
    float cx, float cy, float cz,
    float* out /*12*/)
{
    float bcx = cx - bx, bcy = cy - by, bcz = cz - bz;
    float inv = rsqrtf(bcx*bcx + bcy*bcy + bcz*bcz + 1e-12f);
    bcx *= inv; bcy *= inv; bcz *= inv;
    float bax = bx - ax, bay = by - ay, baz = bz - az;
    float nx = bay*bcz - baz*bcy;
    float ny = baz*bcx - bax*bcz;
    float nz = bax*bcy - bay*bcx;
    inv = rsqrtf(nx*nx + ny*ny + nz*nz + 1e-12f);
    nx *= inv; ny *= inv; nz *= inv;
    float mx = ny*bcz - nz*bcy;
    float my = nz*bcx - nx*bcz;
    float mz = nx*bcy - ny*bcx;
    out[0] = bcx; out[1] = mx; out[2] = nx;
    out[3] = bcy; out[4] = my; out[5] = ny;
    out[6] = bcz; out[7] = mz; out[8] = nz;
    out[9] = cx; out[10] = cy; out[11] = cz;
}

__device__ __forceinline__ void nerf_step(
    float ax, float ay, float az,
    float bx, float by, float bz,
    float cx, float cy, float cz,
    float px, float py, float pz,
    float& ox, float& oy, float& oz)
{
    float bcx = cx - bx, bcy = cy - by, bcz = cz - bz;
    float inv = rsqrtf(bcx*bcx + bcy*bcy + bcz*bcz + 1e-12f);
    bcx *= inv; bcy *= inv; bcz *= inv;
    float bax = bx - ax, bay = by - ay, baz = bz - az;
    float nx = bay*bcz - baz*bcy;
    float ny = baz*bcx - bax*bcz;
    float nz = bax*bcy - bay*bcx;
    inv = rsqrtf(nx*nx + ny*ny + nz*nz + 1e-12f);
    nx *= inv; ny *= inv; nz *= inv;
    float mx = ny*bcz - nz*bcy;
    float my = nz*bcx - nx*bcz;
    float mz = nx*bcy - ny*bcx;
    ox = bcx*px + mx*py + nx*pz + cx;
    oy = bcy*px + my*py + ny*pz + cy;
    oz = bcz*px + mz*py + nz*pz + cz;
}

// Per-lane permuted bond constants. Reshape (L,B,3,3)->(3L,B,3) makes scan
// lane b at residue l, step k consume dih flat[l*1536 + 512k + b]; bond-const
// index = (512k+b)%3 -> pattern d = {b%3, (b+2)%3, (b+1)%3}. (Verified R5.)
__device__ __forceinline__ void lane_consts(int b, float* rcl, float* rsl) {
    const float PI = 3.14159265358979323846f;
    float rc[3], rs[3];
    rc[0] = 145.801f * cosf(PI - 2.124f); rs[0] = 145.801f * sinf(PI - 2.124f);
    rc[1] = 152.326f * cosf(PI - 1.941f); rs[1] = 152.326f * sinf(PI - 1.941f);
    rc[2] = 132.868f * cosf(PI - 2.028f); rs[2] = 132.868f * sinf(PI - 2.028f);
    const int d0 = b % 3, d1 = (b + 2) % 3, d2 = (b + 1) % 3;
    rcl[0] = rc[d0]; rcl[1] = rc[d1]; rcl[2] = rc[d2];
    rsl[0] = rs[d0]; rsl[1] = rs[d1]; rsl[2] = rs[d2];
}

// Single-dispatch grid scan via flag lookback (no cooperative launch — R8
// showed hipLaunchCooperativeKernel no-ops under graph capture).
// Block = (g, btile): GROUP frags x BTILE b-lanes. All 256 blocks co-resident
// (1/CU) -> spin-wait cannot deadlock. Flags poisoned 0xAA pre-launch.
//
// R16: post-mortems R4 (chain 2x -> slower despite no spills) and R6 (BTILE=16
// -> 2x overfetch, VGPR clamp 60) establish: the SERIAL NeRF CHAIN LATENCY is
// the dominant cost; geometry changes keep backfiring via allocator/fetch side
// effects. So: raise ILP inside the thread. Each fragment's 24-step chain is
// split into TWO INDEPENDENT 12-step half-chains from the canonical init
// (recurrence is rigid-motion-equivariant, proven R4/R13-pass). Interleaved in
// one unrolled loop, half-1 fills half-0's dependency bubbles -> stage-1
// latency ~halves. Reassembly: h = H1 o H2; tail transforms half-0 points by
// G, half-1 by G1 = G o H1. Protocol/geometry/loads/stores: R14 verbatim
// (fastest measured: kernel ~36us, total 96.3).
__global__ void __launch_bounds__(GROUP * BTILE) coord_onepass(
    const float* __restrict__ dih, float* __restrict__ T,
    int* __restrict__ flags, float* __restrict__ out)
{
    const int btile = blockIdx.x & (NTILE - 1);
    const int g     = blockIdx.x >> 4;                 // NTILE==16
    const int bsub  = threadIdx.x & (BTILE - 1);
    const int j     = threadIdx.x >> 5;                // BTILE==32
    const int f     = g * GROUP + j;
    const int b     = btile * BTILE + bsub;

    __shared__ float BufA[GROUP * BTILE * 13];         // stride 13: conflict-free
    __shared__ float BufB[GROUP * BTILE * 13];
    float* rowA = &BufA[(size_t)threadIdx.x * 13];
    float* rowB = &BufB[(size_t)threadIdx.x * 13];

    float rcl[3], rsl[3];
    lane_consts(b, rcl, rsl);

    // ---- Prefetch all dihedrals for this fragment ----
    float dd[NPTS];
    #pragma unroll
    for (int r = 0; r < RPF; ++r) {
        const float* src = dih + (size_t)(f * RPF + r) * (3 * BATCH) + b;
        dd[r*3 + 0] = __builtin_nontemporal_load(src);
        dd[r*3 + 1] = __builtin_nontemporal_load(src + BATCH);
        dd[r*3 + 2] = __builtin_nontemporal_load(src + 2 * BATCH);
    }

    // ---- Stage 1: TWO interleaved independent half-chains (ILP=2).
    //      Both start from the canonical init triple; equivariance lets us
    //      splice with H1 later. ----
    float lx[NPTS], ly[NPTS], lz[NPTS];

    const float IAX = -0.70710678118654752f, IAY = 1.22474487139158905f;
    const float IBX = -1.41421356237309505f;

    float a0x = IAX, a0y = IAY, a0z = 0.0f;
    float b0x = IBX, b0y = 0.0f, b0z = 0.0f;
    float c0x = 0.0f, c0y = 0.0f, c0z = 0.0f;
    float a1x = IAX, a1y = IAY, a1z = 0.0f;
    float b1x = IBX, b1y = 0.0f, b1z = 0.0f;
    float c1x = 0.0f, c1y = 0.0f, c1z = 0.0f;

    #pragma unroll
    for (int q = 0; q < HALF; ++q) {
        const int k = q - (q / 3) * 3;                 // q%3; (12+q)%3 == q%3
        float sn0, cs0, sn1, cs1;
        __sincosf(dd[q],        &sn0, &cs0);
        __sincosf(dd[HALF + q], &sn1, &cs1);
        float ox, oy, oz;
        nerf_step(a0x, a0y, a0z, b0x, b0y, b0z, c0x, c0y, c0z,
                  rcl[k], cs0 * rsl[k], sn0 * rsl[k], ox, oy, oz);
        a0x = b0x; a0y = b0y; a0z = b0z;
        b0x = c0x; b0y = c0y; b0z = c0z;
        c0x = ox;  c0y = oy;  c0z = oz;
        lx[q] = ox; ly[q] = oy; lz[q] = oz;
        nerf_step(a1x, a1y, a1z, b1x, b1y, b1z, c1x, c1y, c1z,
                  rcl[k], cs1 * rsl[k], sn1 * rsl[k], ox, oy, oz);
        a1x = b1x; a1y = b1y; a1z = b1z;
        b1x = c1x; b1y = c1y; b1z = c1z;
        c1x = ox;  c1y = oy;  c1z = oz;
        lx[HALF + q] = ox; ly[HALF + q] = oy; lz[HALF + q] = oz;
    }

    float H1[12], cur[12];
    frame_of(a0x, a0y, a0z, b0x, b0y, b0z, c0x, c0y, c0z, H1);
    {
        float H2[12];
        frame_of(a1x, a1y, a1z, b1x, b1y, b1z, c1x, c1y, c1z, H2);
        compose(H1, H2, cur);            // full-fragment frame (inclusive seed)
    }

    // ---- Scan 1: inclusive Hillis-Steele over j, register-tracked,
    //      ping-pong A/B (one barrier per round; WAR-safe) ----
    #pragma unroll
    for (int k = 0; k < 12; ++k) rowA[k] = cur[k];
    __syncthreads();
    if (j >= 1) compose(&BufA[(size_t)(threadIdx.x - 1*BTILE) * 13], cur, cur);

    #pragma unroll
    for (int k = 0; k < 12; ++k) rowB[k] = cur[k];
    __syncthreads();
    if (j >= 2) compose(&BufB[(size_t)(threadIdx.x - 2*BTILE) * 13], cur, cur);

    #pragma unroll
    for (int k = 0; k < 12; ++k) rowA[k] = cur[k];
    __syncthreads();
    if (j >= 4) compose(&BufA[(size_t)(threadIdx.x - 4*BTILE) * 13], cur, cur);

    #pragma unroll
    for (int k = 0; k < 12; ++k) rowB[k] = cur[k];
    __syncthreads();
    if (j >= 8) compose(&BufB[(size_t)(threadIdx.x - 8*BTILE) * 13], cur, cur);

    // final publish of inclusive prefixes -> A
    #pragma unroll
    for (int k = 0; k < 12; ++k) rowA[k] = cur[k];
    __syncthreads();

    // P[f-1] for this thread (row j-1), grabbed before A is reused by scan2
    float pprev[12];
    if (j > 0) {
        #pragma unroll
        for (int k = 0; k < 12; ++k)
            pprev[k] = BufA[(size_t)(threadIdx.x - BTILE) * 13 + k];
    }

    // ---- Publish group total T_g + flag, wave-level release (R14) ----
    if (j == GROUP - 1 && g < NGRP - 1) {
        #pragma unroll
        for (int k = 0; k < 12; ++k)
            __hip_atomic_store(&T[((size_t)g * 12 + k) * BATCH + b], cur[k],
                               __ATOMIC_RELAXED, __HIP_MEMORY_SCOPE_AGENT);
        if (bsub == 0)
            __hip_atomic_store(&flags[g * NTILE + btile], READY,
                               __ATOMIC_RELEASE, __HIP_MEMORY_SCOPE_AGENT);
    }

    // ---- Scan 2 (g>0): parallel exclusive prefix of group totals.
    //      RELAXED spin + ONE acquire fence (R14 measured win). ----
    float G[12];
    if (g == 0) {
        if (j == 0) set_identity(G);
        else {
            #pragma unroll
            for (int k = 0; k < 12; ++k) G[k] = pprev[k];
        }
    } else {
        float cur2[12];
        if (j < g) {
            while (__hip_atomic_load(&flags[j * NTILE + btile],
                                     __ATOMIC_RELAXED, __HIP_MEMORY_SCOPE_AGENT)
                   != READY) {
                __builtin_amdgcn_s_sleep(1);
            }
            __builtin_amdgcn_fence(__ATOMIC_ACQUIRE, "agent");
            #pragma unroll
            for (int k = 0; k < 12; ++k)
                cur2[k] = __hip_atomic_load(&T[((size_t)j * 12 + k) * BATCH + b],
                                            __ATOMIC_RELAXED, __HIP_MEMORY_SCOPE_AGENT);
        } else {
            set_identity(cur2);
        }

        // ping-pong rounds: B, A, B, A
        #pragma unroll
        for (int k = 0; k < 12; ++k) rowB[k] = cur2[k];
        __syncthreads();
        if (j >= 1) compose(&BufB[(size_t)(threadIdx.x - 1*BTILE) * 13], cur2, cur2);

        #pragma unroll
        for (int k = 0; k < 12; ++k) rowA[k] = cur2[k];
        __syncthreads();
        if (j >= 2) compose(&BufA[(size_t)(threadIdx.x - 2*BTILE) * 13], cur2, cur2);

        #pragma unroll
        for (int k = 0; k < 12; ++k) rowB[k] = cur2[k];
        __syncthreads();
        if (j >= 4) compose(&BufB[(size_t)(threadIdx.x - 4*BTILE) * 13], cur2, cur2);

        #pragma unroll
        for (int k = 0; k < 12; ++k) rowA[k] = cur2[k];
        __syncthreads();
        if (j >= 8) compose(&BufA[(size_t)(threadIdx.x - 8*BTILE) * 13], cur2, cur2);

        // broadcast row g-1 (same-address LDS reads across j: free broadcast)
        #pragma unroll
        for (int k = 0; k < 12; ++k) rowB[k] = cur2[k];
        __syncthreads();
        float E[12];
        #pragma unroll
        for (int k = 0; k < 12; ++k)
            E[k] = BufB[(size_t)((g - 1) * BTILE + bsub) * 13 + k];

        if (j == 0) {
            #pragma unroll
            for (int k = 0; k < 12; ++k) G[k] = E[k];
        } else {
            compose(E, pprev, G);
        }
    }

    // ---- Tail: half-0 points by G, half-1 points by G1 = G o H1 ----
    float G1[12];
    compose(G, H1, G1);

    #pragma unroll
    for (int q = 0; q < NPTS; ++q) {
        const float* M = (q < HALF) ? G : G1;
        float ox = lx[q], oy = ly[q], oz = lz[q];
        float gx = M[0]*ox + M[1]*oy + M[2]*oz + M[9];
        float gy = M[3]*ox + M[4]*oy + M[5]*oz + M[10];
        float gz = M[6]*ox + M[7]*oy + M[8]*oz + M[11];
        size_t n = (size_t)f * NPTS + q;               // scan step index
        float* dst = out + (n * BATCH + b) * 3;
        __builtin_nontemporal_store(gx, dst + 0);
        __builtin_nontemporal_store(gy, dst + 1);
        __builtin_nontemporal_store(gz, dst + 2);
    }
}

extern "C" void kernel_launch(void* const* d_in, const int* in_sizes, int n_in,
                              void* d_out, int out_size, void* d_ws, size_t ws_size,
                              hipStream_t stream) {
    const float* dih = (const float*)d_in[0];
    float* out = (float*)d_out;
    float* T = (float*)d_ws;                           // NGRP*12*BATCH floats
    int* flags = (int*)(T + (size_t)NGRP * 12 * BATCH); // NGRP*NTILE ints

    coord_onepass<<<dim3(NGRP * NTILE), dim3(GROUP * BTILE), 0, stream>>>(
        dih, T, flags, out);
    (void)ws_size; (void)n_in; (void)out_size; (void)in_sizes;
}

// Round 8
// 92.896 us; speedup vs baseline: 1.1483x; 1.0434x over previous
//
#include <hip/hip_runtime.h>
#include <math.h>

#define BATCH 512    // post-reshape scan lanes
#define FRAGS 256    // fragments per chain
#define GROUP 16     // fragments per scan group == frags per block
#define NGRP  (FRAGS/GROUP)   // 16 groups
#define BTILE 32     // batch lanes per block
#define NTILE (BATCH/BTILE)   // 16 b-tiles
#define RPF   8      // residues per fragment (L=2048)
#define READY 0x5EADBEEF

// Rigid transform: 12 floats, R row-major r[i*3+j], t=[9..11]. x' = Rx + t.
// compose(A,B): A is the EARLIER prefix, B the later. (Verified R5-R9.)
__device__ __forceinline__ void compose(const float* A, const float* B, float* D) {
    float d[12];
    #pragma unroll
    for (int i = 0; i < 3; ++i) {
        #pragma unroll
        for (int j = 0; j < 3; ++j)
            d[i*3+j] = A[i*3+0]*B[0*3+j] + A[i*3+1]*B[1*3+j] + A[i*3+2]*B[2*3+j];
        d[9+i] = A[i*3+0]*B[9] + A[i*3+1]*B[10] + A[i*3+2]*B[11] + A[9+i];
    }
    #pragma unroll
    for (int k = 0; k < 12; ++k) D[k] = d[k];
}

__device__ __forceinline__ void frame_of(
    float ax, float ay, float az,
    float bx, float by, float bz,
    float cx, float cy, float cz,
    float* out /*12*/)
{
    float bcx = cx - bx, bcy = cy - by, bcz = cz - bz;
    float inv = rsqrtf(bcx*bcx + bcy*bcy + bcz*bcz + 1e-12f);
    bcx *= inv; bcy *= inv; bcz *= inv;
    float bax = bx - ax, bay = by - ay, baz = bz - az;
    float nx = bay*bcz - baz*bcy;
    float ny = baz*bcx - bax*bcz;
    float nz = bax*bcy - bay*bcx;
    inv = rsqrtf(nx*nx + ny*ny + nz*nz + 1e-12f);
    nx *= inv; ny *= inv; nz *= inv;
    float mx = ny*bcz - nz*bcy;
    float my = nz*bcx - nx*bcz;
    float mz = nx*bcy - ny*bcx;
    out[0] = bcx; out[1] = mx; out[2] = nx;
    out[3] = bcy; out[4] = my; out[5] = ny;
    out[6] = bcz; out[7] = mz; out[8] = nz;
    out[9] = cx; out[10] = cy; out[11] = cz;
}

__device__ __forceinline__ void nerf_step(
    float ax, float ay, float az,
    float bx, float by, float bz,
    float cx, float cy, float cz,
    float px, float py, float pz,
    float& ox, float& oy, float& oz)
{
    float bcx = cx - bx, bcy = cy - by, bcz = cz - bz;
    float inv = rsqrtf(bcx*bcx + bcy*bcy + bcz*bcz + 1e-12f);
    bcx *= inv; bcy *= inv; bcz *= inv;
    float bax = bx - ax, bay = by - ay, baz = bz - az;
    float nx = bay*bcz - baz*bcy;
    float ny = baz*bcx - bax*bcz;
    float nz = bax*bcy - bay*bcx;
    inv = rsqrtf(nx*nx + ny*ny + nz*nz + 1e-12f);
    nx *= inv; ny *= inv; nz *= inv;
    float mx = ny*bcz - nz*bcy;
    float my = nz*bcx - nx*bcz;
    float mz = nx*bcy - ny*bcx;
    ox = bcx*px + mx*py + nx*pz + cx;
    oy = bcy*px + my*py + ny*pz + cy;
    oz = bcz*px + mz*py + nz*pz + cz;
}

// Per-lane permuted bond constants. Reshape (L,B,3,3)->(3L,B,3) makes scan
// lane b at residue l, step k consume dih flat[l*1536 + 512k + b]; bond-const
// index = (512k+b)%3 -> pattern d = {b%3, (b+2)%3, (b+1)%3}. (Verified R5.)
__device__ __forceinline__ void lane_consts(int b, float* rcl, float* rsl) {
    const float PI = 3.14159265358979323846f;
    float rc[3], rs[3];
    rc[0] = 145.801f * cosf(PI - 2.124f); rs[0] = 145.801f * sinf(PI - 2.124f);
    rc[1] = 152.326f * cosf(PI - 1.941f); rs[1] = 152.326f * sinf(PI - 1.941f);
    rc[2] = 132.868f * cosf(PI - 2.028f); rs[2] = 132.868f * sinf(PI - 2.028f);
    const int d0 = b % 3, d1 = (b + 2) % 3, d2 = (b + 1) % 3;
    rcl[0] = rc[d0]; rcl[1] = rc[d1]; rcl[2] = rc[d2];
    rsl[0] = rs[d0]; rsl[1] = rs[d1]; rsl[2] = rs[d2];
}

// Single-dispatch grid scan via flag lookback (no cooperative launch — R8
// showed hipLaunchCooperativeKernel no-ops under graph capture).
// Block = (g, btile): GROUP frags x BTILE b-lanes. All 256 blocks co-resident
// (1/CU) -> spin-wait cannot deadlock. Flags live in d_ws (poisoned 0xAA
// before every launch, != READY, so they self-reset).
//
// R17: ledger over R0-R7 (total - kernel == 60.3us harness constant) shows
// the ROUND-0 ARTIFACT was the fastest kernel ever measured (~33.6us); the
// R1 bundle of rewrites cost ~10us and R2-R7 never fully recovered. The one
// isolated, reproducible win is relaxed-spin + single acquire fence
// (R1->R5, structure-identical: 43.9->36.1; acquire-spin emits cache-inv +
// vmcnt-drain per iteration -> device-wide invalidation storm). THIS kernel
// is R0 byte-for-byte with ONLY the spin-loop body changed: relaxed spin,
// then one __builtin_amdgcn_fence(ACQUIRE, "agent") after the flag is seen
// (spinners only; the existing __syncthreads then propagates visibility
// block-wide, exactly as R0 already relied on).
__global__ void __launch_bounds__(GROUP * BTILE) coord_onepass(
    const float* __restrict__ dih, float* __restrict__ T,
    int* __restrict__ flags, float* __restrict__ out)
{
    const int btile = blockIdx.x & (NTILE - 1);
    const int g     = blockIdx.x >> 4;                 // NTILE==16
    const int bsub  = threadIdx.x & (BTILE - 1);
    const int j     = threadIdx.x >> 5;                // BTILE==32
    const int f     = g * GROUP + j;
    const int b     = btile * BTILE + bsub;

    __shared__ float S[GROUP * BTILE * 13];            // stride 13: conflict-free
    float* Srow = &S[(size_t)threadIdx.x * 13];

    float rcl[3], rsl[3];
    lane_consts(b, rcl, rsl);

    // ---- Stage 1: local chain, points kept in registers ----
    float lx[3 * RPF], ly[3 * RPF], lz[3 * RPF];

    float ax = -0.70710678118654752f, ay = 1.22474487139158905f, az = 0.0f;
    float bx = -1.41421356237309505f, by = 0.0f, bz = 0.0f;
    float cx = 0.0f, cy = 0.0f, cz = 0.0f;

    #pragma unroll
    for (int r = 0; r < RPF; ++r) {
        int l = f * RPF + r;
        const float* src = dih + (size_t)l * (3 * BATCH) + b;
        float dd[3];
        dd[0] = src[0];
        dd[1] = src[BATCH];
        dd[2] = src[2 * BATCH];
        #pragma unroll
        for (int k = 0; k < 3; ++k) {
            float sn, cs;
            __sincosf(dd[k], &sn, &cs);
            float ox, oy, oz;
            nerf_step(ax, ay, az, bx, by, bz, cx, cy, cz,
                      rcl[k], cs * rsl[k], sn * rsl[k], ox, oy, oz);
            ax = bx; ay = by; az = bz;
            bx = cx; by = cy; bz = cz;
            cx = ox; cy = oy; cz = oz;
            lx[r * 3 + k] = ox; ly[r * 3 + k] = oy; lz[r * 3 + k] = oz;
        }
    }

    {
        float h[12];
        frame_of(ax, ay, az, bx, by, bz, cx, cy, cz, h);
        #pragma unroll
        for (int k = 0; k < 12; ++k) Srow[k] = h[k];
    }
    __syncthreads();

    // ---- In-block Hillis-Steele inclusive scan over j (non-commutative) ----
    float tmp[12];
    #pragma unroll
    for (int o = 1; o < GROUP; o <<= 1) {
        const bool act = (j >= o);
        if (act) compose(&S[(size_t)(threadIdx.x - o * BTILE) * 13], Srow, tmp);
        __syncthreads();
        if (act) {
            #pragma unroll
            for (int k = 0; k < 12; ++k) Srow[k] = tmp[k];
        }
        __syncthreads();
    }

    // ---- Publish group total T_g (j==GROUP-1 rows), then release flag ----
    if (j == GROUP - 1) {
        #pragma unroll
        for (int k = 0; k < 12; ++k)
            __hip_atomic_store(&T[((size_t)g * 12 + k) * BATCH + b], Srow[k],
                               __ATOMIC_RELAXED, __HIP_MEMORY_SCOPE_AGENT);
    }
    __syncthreads();
    if (threadIdx.x == 0)
        __hip_atomic_store(&flags[g * NTILE + btile], READY,
                           __ATOMIC_RELEASE, __HIP_MEMORY_SCOPE_AGENT);

    // ---- Lookback: wait for all predecessor groups' totals.
    //      R17 change (THE ONLY DIFF vs R0): relaxed spin + one acquire
    //      fence after the flag is observed — kills the per-iteration
    //      cache-invalidate/vmcnt-drain storm of an acquire-spin. ----
    if (g > 0) {
        if ((int)threadIdx.x < g) {
            while (__hip_atomic_load(&flags[threadIdx.x * NTILE + btile],
                                     __ATOMIC_RELAXED, __HIP_MEMORY_SCOPE_AGENT)
                   != READY) {
                __builtin_amdgcn_s_sleep(1);
            }
            __builtin_amdgcn_fence(__ATOMIC_ACQUIRE, "agent");
        }
        __syncthreads();
    }

    // ---- E_g = T_0 o ... o T_{g-1}; G = E_g o S[j-1] ----
    float G[12];
    if (g == 0) {
        G[0]=1.f; G[1]=0.f; G[2]=0.f;
        G[3]=0.f; G[4]=1.f; G[5]=0.f;
        G[6]=0.f; G[7]=0.f; G[8]=1.f;
        G[9]=0.f; G[10]=0.f; G[11]=0.f;
    } else {
        #pragma unroll
        for (int k = 0; k < 12; ++k)
            G[k] = __hip_atomic_load(&T[(size_t)k * BATCH + b],
                                     __ATOMIC_RELAXED, __HIP_MEMORY_SCOPE_AGENT);
        for (int gp = 1; gp < g; ++gp) {
            float tg[12];
            #pragma unroll
            for (int k = 0; k < 12; ++k)
                tg[k] = __hip_atomic_load(&T[((size_t)gp * 12 + k) * BATCH + b],
                                          __ATOMIC_RELAXED, __HIP_MEMORY_SCOPE_AGENT);
            compose(G, tg, G);
        }
    }
    if (j > 0) {
        // P[f-1] == inclusive prefix row of thread (j-1, bsub), still in LDS.
        compose(G, &S[(size_t)(threadIdx.x - BTILE) * 13], G);
    }

    // ---- Transform register-held points, coalesced stores ----
    #pragma unroll
    for (int q = 0; q < 3 * RPF; ++q) {
        float ox = lx[q], oy = ly[q], oz = lz[q];
        float gx = G[0]*ox + G[1]*oy + G[2]*oz + G[9];
        float gy = G[3]*ox + G[4]*oy + G[5]*oz + G[10];
        float gz = G[6]*ox + G[7]*oy + G[8]*oz + G[11];
        size_t n = (size_t)f * (3 * RPF) + q;            // scan step index
        float* dst = out + (n * BATCH + b) * 3;
        dst[0] = gx; dst[1] = gy; dst[2] = gz;
    }
}

extern "C" void kernel_launch(void* const* d_in, const int* in_sizes, int n_in,
                              void* d_out, int out_size, void* d_ws, size_t ws_size,
                              hipStream_t stream) {
    const float* dih = (const float*)d_in[0];
    float* out = (float*)d_out;
    float* T = (float*)d_ws;                           // NGRP*12*BATCH floats
    int* flags = (int*)(T + (size_t)NGRP * 12 * BATCH); // NGRP*NTILE ints

    coord_onepass<<<dim3(NGRP * NTILE), dim3(GROUP * BTILE), 0, stream>>>(
        dih, T, flags, out);
    (void)ws_size; (void)n_in; (void)out_size; (void)in_sizes;
}

// Round 9
// 92.771 us; speedup vs baseline: 1.1499x; 1.0014x over previous
//
#include <hip/hip_runtime.h>
#include <math.h>

#define BATCH 512    // post-reshape scan lanes
#define FRAGS 256    // fragments per chain
#define GROUP 16     // fragments per scan group == frags per block
#define NGRP  (FRAGS/GROUP)   // 16 groups
#define BTILE 32     // batch lanes per block
#define NTILE (BATCH/BTILE)   // 16 b-tiles
#define RPF   8      // residues per fragment (L=2048)
#define READY 0x5EADBEEF

// Rigid transform: 12 floats, R row-major r[i*3+j], t=[9..11]. x' = Rx + t.
// compose(A,B): A is the EARLIER prefix, B the later. (Verified R5-R9.)
__device__ __forceinline__ void compose(const float* A, const float* B, float* D) {
    float d[12];
    #pragma unroll
    for (int i = 0; i < 3; ++i) {
        #pragma unroll
        for (int j = 0; j < 3; ++j)
            d[i*3+j] = A[i*3+0]*B[0*3+j] + A[i*3+1]*B[1*3+j] + A[i*3+2]*B[2*3+j];
        d[9+i] = A[i*3+0]*B[9] + A[i*3+1]*B[10] + A[i*3+2]*B[11] + A[9+i];
    }
    #pragma unroll
    for (int k = 0; k < 12; ++k) D[k] = d[k];
}

__device__ __forceinline__ void frame_of(
    float ax, float ay, float az,
    float bx, float by, float bz,
    float cx, float cy, float cz,
    float* out /*12*/)
{
    float bcx = cx - bx, bcy = cy - by, bcz = cz - bz;
    float inv = rsqrtf(bcx*bcx + bcy*bcy + bcz*bcz + 1e-12f);
    bcx *= inv; bcy *= inv; bcz *= inv;
    float bax = bx - ax, bay = by - ay, baz = bz - az;
    float nx = bay*bcz - baz*bcy;
    float ny = baz*bcx - bax*bcz;
    float nz = bax*bcy - bay*bcx;
    inv = rsqrtf(nx*nx + ny*ny + nz*nz + 1e-12f);
    nx *= inv; ny *= inv; nz *= inv;
    float mx = ny*bcz - nz*bcy;
    float my = nz*bcx - nx*bcz;
    float mz = nx*bcy - ny*bcx;
    out[0] = bcx; out[1] = mx; out[2] = nx;
    out[3] = bcy; out[4] = my; out[5] = ny;
    out[6] = bcz; out[7] = mz; out[8] = nz;
    out[9] = cx; out[10] = cy; out[11] = cz;
}

__device__ __forceinline__ void nerf_step(
    float ax, float ay, float az,
    float bx, float by, float bz,
    float cx, float cy, float cz,
    float px, float py, float pz,
    float& ox, float& oy, float& oz)
{
    float bcx = cx - bx, bcy = cy - by, bcz = cz - bz;
    float inv = rsqrtf(bcx*bcx + bcy*bcy + bcz*bcz + 1e-12f);
    bcx *= inv; bcy *= inv; bcz *= inv;
    float bax = bx - ax, bay = by - ay, baz = bz - az;
    float nx = bay*bcz - baz*bcy;
    float ny = baz*bcx - bax*bcz;
    float nz = bax*bcy - bay*bcx;
    inv = rsqrtf(nx*nx + ny*ny + nz*nz + 1e-12f);
    nx *= inv; ny *= inv; nz *= inv;
    float mx = ny*bcz - nz*bcy;
    float my = nz*bcx - nx*bcz;
    float mz = nx*bcy - ny*bcx;
    ox = bcx*px + mx*py + nx*pz + cx;
    oy = bcy*px + my*py + ny*pz + cy;
    oz = bcz*px + mz*py + nz*pz + cz;
}

// Per-lane permuted bond constants. Reshape (L,B,3,3)->(3L,B,3) makes scan
// lane b at residue l, step k consume dih flat[l*1536 + 512k + b]; bond-const
// index = (512k+b)%3 -> pattern d = {b%3, (b+2)%3, (b+1)%3}. (Verified R5.)
__device__ __forceinline__ void lane_consts(int b, float* rcl, float* rsl) {
    const float PI = 3.14159265358979323846f;
    float rc[3], rs[3];
    rc[0] = 145.801f * cosf(PI - 2.124f); rs[0] = 145.801f * sinf(PI - 2.124f);
    rc[1] = 152.326f * cosf(PI - 1.941f); rs[1] = 152.326f * sinf(PI - 1.941f);
    rc[2] = 132.868f * cosf(PI - 2.028f); rs[2] = 132.868f * sinf(PI - 2.028f);
    const int d0 = b % 3, d1 = (b + 2) % 3, d2 = (b + 1) % 3;
    rcl[0] = rc[d0]; rcl[1] = rc[d1]; rcl[2] = rc[d2];
    rsl[0] = rs[d0]; rsl[1] = rs[d1]; rsl[2] = rs[d2];
}

// Single-dispatch grid scan via flag lookback (no cooperative launch — R8
// showed hipLaunchCooperativeKernel no-ops under graph capture).
// Block = (g, btile): GROUP frags x BTILE b-lanes. All 256 blocks co-resident
// (1/CU) -> spin-wait cannot deadlock. Flags live in d_ws (poisoned 0xAA
// before every launch, != READY, so they self-reset).
//
// R18 = R17 (best total, 92.9) with ONE change: the lookback E_g chain was
// computed redundantly by ALL 512 threads (E_g depends only on b, shared by
// all 16 j-rows at a bsub) -> 16x the agent-scope L2 loads, 23.6M grid-wide
// in a few-us window where all 256 blocks hammer the 400KB T region
// simultaneously. Now ONLY row j==0 (lanes 0-31 of wave 0 — the wave that
// already contains the spinners, so wave-lockstep orders spin->loads for
// free) computes E_g, broadcasts via a 1.7KB LDS buffer; the old post-spin
// barrier becomes the broadcast barrier (barrier count unchanged).
// Kept from R17: relaxed spin + one acquire fence (R1->R5 isolated win).
__global__ void __launch_bounds__(GROUP * BTILE) coord_onepass(
    const float* __restrict__ dih, float* __restrict__ T,
    int* __restrict__ flags, float* __restrict__ out)
{
    const int btile = blockIdx.x & (NTILE - 1);
    const int g     = blockIdx.x >> 4;                 // NTILE==16
    const int bsub  = threadIdx.x & (BTILE - 1);
    const int j     = threadIdx.x >> 5;                // BTILE==32
    const int f     = g * GROUP + j;
    const int b     = btile * BTILE + bsub;

    __shared__ float S[GROUP * BTILE * 13];            // stride 13: conflict-free
    __shared__ float Elds[BTILE * 13];                 // E_g broadcast buffer
    float* Srow = &S[(size_t)threadIdx.x * 13];

    float rcl[3], rsl[3];
    lane_consts(b, rcl, rsl);

    // ---- Stage 1: local chain, points kept in registers ----
    float lx[3 * RPF], ly[3 * RPF], lz[3 * RPF];

    float ax = -0.70710678118654752f, ay = 1.22474487139158905f, az = 0.0f;
    float bx = -1.41421356237309505f, by = 0.0f, bz = 0.0f;
    float cx = 0.0f, cy = 0.0f, cz = 0.0f;

    #pragma unroll
    for (int r = 0; r < RPF; ++r) {
        int l = f * RPF + r;
        const float* src = dih + (size_t)l * (3 * BATCH) + b;
        float dd[3];
        dd[0] = src[0];
        dd[1] = src[BATCH];
        dd[2] = src[2 * BATCH];
        #pragma unroll
        for (int k = 0; k < 3; ++k) {
            float sn, cs;
            __sincosf(dd[k], &sn, &cs);
            float ox, oy, oz;
            nerf_step(ax, ay, az, bx, by, bz, cx, cy, cz,
                      rcl[k], cs * rsl[k], sn * rsl[k], ox, oy, oz);
            ax = bx; ay = by; az = bz;
            bx = cx; by = cy; bz = cz;
            cx = ox; cy = oy; cz = oz;
            lx[r * 3 + k] = ox; ly[r * 3 + k] = oy; lz[r * 3 + k] = oz;
        }
    }

    {
        float h[12];
        frame_of(ax, ay, az, bx, by, bz, cx, cy, cz, h);
        #pragma unroll
        for (int k = 0; k < 12; ++k) Srow[k] = h[k];
    }
    __syncthreads();

    // ---- In-block Hillis-Steele inclusive scan over j (non-commutative) ----
    float tmp[12];
    #pragma unroll
    for (int o = 1; o < GROUP; o <<= 1) {
        const bool act = (j >= o);
        if (act) compose(&S[(size_t)(threadIdx.x - o * BTILE) * 13], Srow, tmp);
        __syncthreads();
        if (act) {
            #pragma unroll
            for (int k = 0; k < 12; ++k) Srow[k] = tmp[k];
        }
        __syncthreads();
    }

    // ---- Publish group total T_g (j==GROUP-1 rows), then release flag ----
    if (j == GROUP - 1) {
        #pragma unroll
        for (int k = 0; k < 12; ++k)
            __hip_atomic_store(&T[((size_t)g * 12 + k) * BATCH + b], Srow[k],
                               __ATOMIC_RELAXED, __HIP_MEMORY_SCOPE_AGENT);
    }
    __syncthreads();
    if (threadIdx.x == 0)
        __hip_atomic_store(&flags[g * NTILE + btile], READY,
                           __ATOMIC_RELEASE, __HIP_MEMORY_SCOPE_AGENT);

    // ---- Lookback: spinners are lanes 0..g-1 of wave 0 (relaxed spin, one
    //      acquire fence — R17's isolated win). Then ONLY row j==0 (same
    //      wave; lockstep orders spin->loads) computes E_g and broadcasts
    //      through LDS. 16x less agent-scope T traffic than R17. ----
    float G[12];
    if (g > 0) {
        if ((int)threadIdx.x < g) {
            while (__hip_atomic_load(&flags[threadIdx.x * NTILE + btile],
                                     __ATOMIC_RELAXED, __HIP_MEMORY_SCOPE_AGENT)
                   != READY) {
                __builtin_amdgcn_s_sleep(1);
            }
        }
        if (j == 0) {
            __builtin_amdgcn_fence(__ATOMIC_ACQUIRE, "agent");
            float E[12];
            #pragma unroll
            for (int k = 0; k < 12; ++k)
                E[k] = __hip_atomic_load(&T[(size_t)k * BATCH + b],
                                         __ATOMIC_RELAXED, __HIP_MEMORY_SCOPE_AGENT);
            for (int gp = 1; gp < g; ++gp) {
                float tg[12];
                #pragma unroll
                for (int k = 0; k < 12; ++k)
                    tg[k] = __hip_atomic_load(&T[((size_t)gp * 12 + k) * BATCH + b],
                                              __ATOMIC_RELAXED, __HIP_MEMORY_SCOPE_AGENT);
                compose(E, tg, E);
            }
            #pragma unroll
            for (int k = 0; k < 12; ++k) Elds[bsub * 13 + k] = E[k];
        }
        __syncthreads();
        #pragma unroll
        for (int k = 0; k < 12; ++k) G[k] = Elds[bsub * 13 + k];
    } else {
        G[0]=1.f; G[1]=0.f; G[2]=0.f;
        G[3]=0.f; G[4]=1.f; G[5]=0.f;
        G[6]=0.f; G[7]=0.f; G[8]=1.f;
        G[9]=0.f; G[10]=0.f; G[11]=0.f;
    }
    if (j > 0) {
        // P[f-1] == inclusive prefix row of thread (j-1, bsub), still in LDS.
        compose(G, &S[(size_t)(threadIdx.x - BTILE) * 13], G);
    }

    // ---- Transform register-held points, coalesced stores ----
    #pragma unroll
    for (int q = 0; q < 3 * RPF; ++q) {
        float ox = lx[q], oy = ly[q], oz = lz[q];
        float gx = G[0]*ox + G[1]*oy + G[2]*oz + G[9];
        float gy = G[3]*ox + G[4]*oy + G[5]*oz + G[10];
        float gz = G[6]*ox + G[7]*oy + G[8]*oz + G[11];
        size_t n = (size_t)f * (3 * RPF) + q;            // scan step index
        float* dst = out + (n * BATCH + b) * 3;
        dst[0] = gx; dst[1] = gy; dst[2] = gz;
    }
}

extern "C" void kernel_launch(void* const* d_in, const int* in_sizes, int n_in,
                              void* d_out, int out_size, void* d_ws, size_t ws_size,
                              hipStream_t stream) {
    const float* dih = (const float*)d_in[0];
    float* out = (float*)d_out;
    float* T = (float*)d_ws;                           // NGRP*12*BATCH floats
    int* flags = (int*)(T + (size_t)NGRP * 12 * BATCH); // NGRP*NTILE ints

    coord_onepass<<<dim3(NGRP * NTILE), dim3(GROUP * BTILE), 0, stream>>>(
        dih, T, flags, out);
    (void)ws_size; (void)n_in; (void)out_size; (void)in_sizes;
}